// Round 28
// baseline (278.109 us; speedup 1.0000x reference)
//
#include <hip/hip_runtime.h>
#include <math.h>

// ---------------------------------------------------------------------------
// SiReN loss on MI355X — round 28: k_bucket v2 with block-local counting sort.
// Pass2 stages records bucket-sorted in LDS; copy-out is coalesced (wave ->
// ~5 transactions instead of 64 scattered stores). Geometry/layout unchanged.
// ---------------------------------------------------------------------------

typedef unsigned int uint;
typedef unsigned short ushort;
typedef unsigned long long ull;
typedef __attribute__((ext_vector_type(8))) short short8v;
typedef __attribute__((ext_vector_type(4))) float float4v;
typedef __attribute__((ext_vector_type(2))) float float2v;

#define BK_SHIFT 9
#define BK_SIZE 512
#define CAP 20480
#define SRC_BITS 18
#define SRC_MASK ((1u << SRC_BITS) - 1u)
#define CHUNK_MAX 6272      // >= ceil(3.2M / 512)

#if __has_builtin(__builtin_amdgcn_cvt_pk_f32_fp8) && __has_builtin(__builtin_amdgcn_cvt_pk_fp8_f32)
#define HW_FP8 1
#else
#define HW_FP8 0
#endif

__device__ inline float b2f(ushort u) { return __uint_as_float(((uint)u) << 16); }
__device__ inline ushort f2b(float f) {
  uint u = __float_as_uint(f);
  return (ushort)((u + 0x7fffu + ((u >> 16) & 1u)) >> 16);
}
__device__ inline uint pack2(float lo, float hi) {
  return (uint)f2b(lo) | ((uint)f2b(hi) << 16);
}

// ---- fp8 e4m3 helpers ----
__device__ inline float dec1(uint u) {
  uint e = (u >> 3) & 0xFu;
  uint m = u & 7u;
  uint s = (u & 0x80u) << 24;
  float norm = __uint_as_float(s | ((e + 120u) << 23) | (m << 20));
  float den = __uint_as_float(s | 0x3F800000u) * (float)(int)m * 0.001953125f;
  return e ? norm : den;
}
__device__ inline uint enc1(float x) {
  uint s = (__float_as_uint(x) >> 24) & 0x80u;
  float ax = fminf(fabsf(x), 448.f);
  uint r;
  if (ax < 0.015625f) {
    r = (uint)(int)rintf(ax * 512.f);
  } else {
    uint b = __float_as_uint(ax);
    b += 0x7FFFFu + ((b >> 20) & 1u);
    uint e = (b >> 23) - 120u;
    r = (e > 15u) ? 0x7Eu : ((e << 3) | ((b >> 20) & 7u));
  }
  return s | r;
}
__device__ inline float4 dec4(uint v) {
#if HW_FP8
  float2v lo = __builtin_amdgcn_cvt_pk_f32_fp8((int)v, false);
  float2v hi = __builtin_amdgcn_cvt_pk_f32_fp8((int)v, true);
  return make_float4(lo[0], lo[1], hi[0], hi[1]);
#else
  return make_float4(dec1(v & 0xFFu), dec1((v >> 8) & 0xFFu),
                     dec1((v >> 16) & 0xFFu), dec1(v >> 24));
#endif
}
__device__ inline uint enc4f(float a, float b, float c, float d) {
#if HW_FP8
  int v = 0;
  v = __builtin_amdgcn_cvt_pk_fp8_f32(a, b, v, false);
  v = __builtin_amdgcn_cvt_pk_fp8_f32(c, d, v, true);
  return (uint)v;
#else
  return enc1(a) | (enc1(b) << 8) | (enc1(c) << 16) | (enc1(d) << 24);
#endif
}

// fused converter: E -> E8s (fp8, pre-scaled by dinv) + Ebf (bf16), E2 -> E2h.
__global__ void k_conv(const float* __restrict__ E, const float* __restrict__ E2,
                       const float* __restrict__ dinv,
                       uint* __restrict__ E8s, ushort* __restrict__ Ebf,
                       ushort* __restrict__ E2h, int n4) {
  int i = blockIdx.x * blockDim.x + threadIdx.x;
  if (i >= n4) return;
  int node = i >> 2;
  float dn = dinv[node];
  const float4* pe = (const float4*)(E + (size_t)i * 16);
  float4 f0 = pe[0], f1 = pe[1], f2 = pe[2], f3 = pe[3];
  uint4 o8;
  o8.x = enc4f(dn * f0.x, dn * f0.y, dn * f0.z, dn * f0.w);
  o8.y = enc4f(dn * f1.x, dn * f1.y, dn * f1.z, dn * f1.w);
  o8.z = enc4f(dn * f2.x, dn * f2.y, dn * f2.z, dn * f2.w);
  o8.w = enc4f(dn * f3.x, dn * f3.y, dn * f3.z, dn * f3.w);
  ((uint4*)E8s)[i] = o8;
  uint4 h0, h1;
  h0.x = pack2(f0.x, f0.y); h0.y = pack2(f0.z, f0.w);
  h0.z = pack2(f1.x, f1.y); h0.w = pack2(f1.z, f1.w);
  h1.x = pack2(f2.x, f2.y); h1.y = pack2(f2.z, f2.w);
  h1.z = pack2(f3.x, f3.y); h1.w = pack2(f3.z, f3.w);
  ((uint4*)Ebf)[2 * i] = h0;
  ((uint4*)Ebf)[2 * i + 1] = h1;
  const float4* p2 = (const float4*)(E2 + (size_t)i * 16);
  float4 g0 = p2[0], g1 = p2[1], g2 = p2[2], g3 = p2[3];
  uint4 e0, e1;
  e0.x = pack2(g0.x, g0.y); e0.y = pack2(g0.z, g0.w);
  e0.z = pack2(g1.x, g1.y); e0.w = pack2(g1.z, g1.w);
  e1.x = pack2(g2.x, g2.y); e1.y = pack2(g2.z, g2.w);
  e1.z = pack2(g3.x, g3.y); e1.w = pack2(g3.z, g3.w);
  ((uint4*)E2h)[2 * i] = e0;
  ((uint4*)E2h)[2 * i + 1] = e1;
}

// weights: Wm (8192) then AW (4096) -> bf16, thread handles 8 elems
__global__ void k_convw(const float* __restrict__ Wm, const float* __restrict__ AW,
                        ushort* __restrict__ Wmh, ushort* __restrict__ AWh) {
  int i = blockIdx.x * blockDim.x + threadIdx.x;
  const float* srcp;
  ushort* dstp;
  if (i < 1024) { srcp = Wm + (size_t)i * 8; dstp = Wmh + (size_t)i * 8; }
  else if (i < 1536) { srcp = AW + (size_t)(i - 1024) * 8; dstp = AWh + (size_t)(i - 1024) * 8; }
  else return;
  float4 a = ((const float4*)srcp)[0], b = ((const float4*)srcp)[1];
  uint4 o;
  o.x = pack2(a.x, a.y); o.y = pack2(a.z, a.w);
  o.z = pack2(b.x, b.y); o.w = pack2(b.z, b.w);
  *(uint4*)dstp = o;
}

// ---------------------------------------------------------------------------
// k_bucket v2: histogram -> scan -> reserve -> LDS-staged local counting sort
// -> coalesced copy-out. 4B record: (dl << 18) | src.
// ---------------------------------------------------------------------------
__global__ __launch_bounds__(512) void k_bucket(const int* __restrict__ src,
                                                const int* __restrict__ dst,
                                                int* __restrict__ gcursor,
                                                uint* __restrict__ ebuf,
                                                int NE, int nbkt, int chunk) {
  __shared__ uint stage[CHUNK_MAX];
  __shared__ int hist[512];     // counts, then reused as local cursor
  __shared__ int lbase[513];    // exclusive prefix (local)
  __shared__ int gbase[512];    // reserved global base per bucket
  __shared__ int sm[512];
  int tid = threadIdx.x;
  int nt = blockDim.x;
  for (int g = tid; g < 512; g += nt) hist[g] = 0;
  __syncthreads();
  int lo = blockIdx.x * chunk;
  int hi = min(lo + chunk, NE);
  for (int e = lo + tid; e < hi; e += nt)
    atomicAdd(&hist[dst[e] >> BK_SHIFT], 1);
  __syncthreads();
  // exclusive scan over nbkt entries (512-wide Hillis-Steele)
  int v = (tid < nbkt) ? hist[tid] : 0;
  sm[tid] = v;
  __syncthreads();
  for (int off = 1; off < 512; off <<= 1) {
    int a = (tid >= off) ? sm[tid - off] : 0;
    __syncthreads();
    sm[tid] += a;
    __syncthreads();
  }
  if (tid < nbkt) lbase[tid] = sm[tid] - v;
  if (tid == 0) lbase[nbkt] = sm[511];
  // reserve global space; reset hist as local cursor
  if (tid < nbkt) {
    gbase[tid] = (v > 0) ? atomicAdd(&gcursor[tid], v) : 0;
    hist[tid] = 0;
  }
  __syncthreads();
  // pass 2: stage records bucket-sorted into LDS
  for (int e = lo + tid; e < hi; e += nt) {
    int d = dst[e];
    int g = d >> BK_SHIFT;
    int pos = atomicAdd(&hist[g], 1);
    stage[lbase[g] + pos] = ((uint)(d & (BK_SIZE - 1)) << SRC_BITS) | (uint)src[e];
  }
  __syncthreads();
  // coalesced copy-out: consecutive i -> consecutive global within a run
  int total = lbase[nbkt];
  for (int i = tid; i < total; i += nt) {
    int loI = 0, hiI = nbkt;
    while (hiI - loI > 1) {
      int mid = (loI + hiI) >> 1;
      if (lbase[mid] <= i) loI = mid; else hiI = mid;
    }
    int g = loI;
    int off = gbase[g] + (i - lbase[g]);
    if (off < CAP)
      ebuf[(size_t)g * CAP + off] = stage[i];
  }
}

// exclusive scan of bucket totals (nbkt <= 1024), single block
__global__ void k_small(const int* __restrict__ gcursor, int* __restrict__ bktbase,
                        int nbkt) {
  __shared__ int sm[1024];
  int t = threadIdx.x;
  int v = (t < nbkt) ? gcursor[t] : 0;
  sm[t] = v;
  __syncthreads();
  for (int off = 1; off < 1024; off <<= 1) {
    int a = (t >= off) ? sm[t - off] : 0;
    __syncthreads();
    sm[t] += a;
    __syncthreads();
  }
  if (t < nbkt) bktbase[t] = sm[t] - v;
  if (t == 0) bktbase[nbkt] = sm[1023];
}

// per-bucket: LDS count -> LDS scan -> rowptr+dinv, then place csrc
__global__ __launch_bounds__(256) void k_fine(const uint* __restrict__ ebuf,
                                              const int* __restrict__ gcursor,
                                              const int* __restrict__ bktbase,
                                              int* __restrict__ rowptr,
                                              float* __restrict__ dinv,
                                              int* __restrict__ csrc,
                                              int NN, int nbkt) {
  __shared__ int degl[BK_SIZE];
  __shared__ int lpl[BK_SIZE];
  __shared__ int ssum[256];
  int g = blockIdx.x;
  int tid = threadIdx.x;
  int cnt = gcursor[g];
  int base = bktbase[g];
  size_t ebase = (size_t)g * CAP;
  for (int j = tid; j < BK_SIZE; j += 256) degl[j] = 0;
  __syncthreads();
  for (int i = tid; i < cnt; i += 256)
    atomicAdd(&degl[(int)(ebuf[ebase + i] >> SRC_BITS)], 1);
  __syncthreads();
  int d0 = degl[2 * tid], d1 = degl[2 * tid + 1];
  int s = d0 + d1;
  ssum[tid] = s;
  __syncthreads();
  for (int off = 1; off < 256; off <<= 1) {
    int a = (tid >= off) ? ssum[tid - off] : 0;
    __syncthreads();
    ssum[tid] += a;
    __syncthreads();
  }
  int excl = ssum[tid] - s;
  lpl[2 * tid] = excl;
  lpl[2 * tid + 1] = excl + d0;
  int node0 = g * BK_SIZE;
  int n0 = node0 + 2 * tid, n1 = n0 + 1;
  if (n0 < NN) {
    rowptr[n0] = base + excl;
    dinv[n0] = (d0 > 0) ? rsqrtf((float)d0) : 0.f;
  }
  if (n1 < NN) {
    rowptr[n1] = base + excl + d0;
    dinv[n1] = (d1 > 0) ? rsqrtf((float)d1) : 0.f;
  }
  if (g == nbkt - 1 && tid == 255) rowptr[NN] = base + excl + d0 + d1;
  __syncthreads();
  for (int i = tid; i < cnt; i += 256) {
    uint e = ebuf[ebase + i];
    int dl = (int)(e >> SRC_BITS);
    int r = atomicAdd(&lpl[dl], 1);
    csrc[base + r] = (int)(e & SRC_MASK);
  }
}

// 16-lane sub-group per node; pre-scaled fp8 rows, no per-edge dinv.
__global__ __launch_bounds__(256) void k_gather(const uint* __restrict__ x,
                                                const int* __restrict__ rowptr,
                                                const int* __restrict__ csrc,
                                                const float* __restrict__ dinv,
                                                uint* __restrict__ out1,
                                                uint* __restrict__ outs, int NN) {
  int gid = blockIdx.x * blockDim.x + threadIdx.x;
  int node = gid >> 4;
  if (node >= NN) return;
  int sl = gid & 15;
  int beg = rowptr[node], end = rowptr[node + 1];
  float dn = dinv[node];
  float a0 = 0.f, a1 = 0.f, a2 = 0.f, a3 = 0.f;
  int i = beg;
  for (; i + 3 < end; i += 4) {
    int s0 = csrc[i], s1 = csrc[i + 1], s2 = csrc[i + 2], s3 = csrc[i + 3];
    uint r0 = x[(size_t)s0 * 16 + sl];
    uint r1 = x[(size_t)s1 * 16 + sl];
    uint r2 = x[(size_t)s2 * 16 + sl];
    uint r3 = x[(size_t)s3 * 16 + sl];
    float4 d0 = dec4(r0), d1 = dec4(r1), d2 = dec4(r2), d3 = dec4(r3);
    a0 += d0.x + d1.x + d2.x + d3.x;
    a1 += d0.y + d1.y + d2.y + d3.y;
    a2 += d0.z + d1.z + d2.z + d3.z;
    a3 += d0.w + d1.w + d2.w + d3.w;
  }
  for (; i < end; ++i) {
    float4 d0 = dec4(x[(size_t)csrc[i] * 16 + sl]);
    a0 += d0.x; a1 += d0.y; a2 += d0.z; a3 += d0.w;
  }
  out1[(size_t)node * 16 + sl] = enc4f(a0 * dn, a1 * dn, a2 * dn, a3 * dn);
  if (outs) {
    float dn2 = dn * dn;
    outs[(size_t)node * 16 + sl] = enc4f(a0 * dn2, a1 * dn2, a2 * dn2, a3 * dn2);
  }
}

// ---------------------------------------------------------------------------
// k_node (MFMA bf16): bf16 E2h A-loads, bf16 Ebf + fp8 b1/b2 ZP; Z packed to
// fp8 (Z8) via an LDS pass (64B rows for k_score).
// ---------------------------------------------------------------------------
__device__ inline float fast_tanh(float x) {
  float t = __expf(fminf(fmaxf(2.f * x, -30.f), 30.f));
  return (t - 1.f) / (t + 1.f);
}

#define MFMA(a, b, c) __builtin_amdgcn_mfma_f32_16x16x32_bf16((a), (b), (c), 0, 0, 0)

__global__ __launch_bounds__(256, 2) void k_node(const ushort* __restrict__ Ebf,
                                                 const ushort* __restrict__ E2h,
                                                 const ushort* __restrict__ Wmh,
                                                 const float* __restrict__ bm,
                                                 const ushort* __restrict__ AWh,
                                                 const float* __restrict__ ab,
                                                 const float* __restrict__ qw,
                                                 const uint* __restrict__ b1q,
                                                 const uint* __restrict__ b2q,
                                                 uint* __restrict__ Z8,
                                                 int NN) {
  __shared__ ushort Hl[64 * 72];
  __shared__ ushort Pl[64 * 72];
  int tid = threadIdx.x;
  int lane = tid & 63, wid = tid >> 6;
  int r15 = lane & 15, kg = lane >> 4;
  int node0 = blockIdx.x * 64;

  // ---- GEMM1: acc = E2 @ W0^T + b0 ----
  int arow = node0 + 16 * wid + r15;
  int arowc = min(arow, NN - 1);
  const ushort* e2p = E2h + (size_t)arowc * 64 + 8 * kg;
  short8v a0 = *(const short8v*)e2p;
  short8v a1 = *(const short8v*)(e2p + 32);
  float4v acc[4];
#pragma unroll
  for (int b = 0; b < 4; ++b) {
    int col = r15 + 16 * b;
    short8v w0 = *(const short8v*)&Wmh[col * 64 + 8 * kg];
    short8v w1 = *(const short8v*)&Wmh[col * 64 + 32 + 8 * kg];
    float bias = bm[col];
    acc[b] = (float4v){bias, bias, bias, bias};
    acc[b] = MFMA(a0, w0, acc[b]);
    acc[b] = MFMA(a1, w1, acc[b]);
  }
#pragma unroll
  for (int b = 0; b < 4; ++b)
#pragma unroll
    for (int rr = 0; rr < 4; ++rr)
      Hl[(16 * wid + 4 * kg + rr) * 72 + 16 * b + r15] = f2b(fmaxf(acc[b][rr], 0.f));

  // stage ZP = (E + b1 + b2)/3 -> Pl (bf16); E bf16, b1/b2 fp8
  {
    int row = tid >> 2;
    int c4 = (tid & 3) * 4;
    int node = node0 + row;
    uint outp[8];
    if (node < NN) {
      const ushort* pe = Ebf + (size_t)node * 64 + c4 * 4;
      uint4 eh0 = *(const uint4*)pe;
      uint4 eh1 = *(const uint4*)(pe + 8);
      uint4 q1 = *(const uint4*)(b1q + (size_t)node * 16 + c4);
      uint4 q2 = *(const uint4*)(b2q + (size_t)node * 16 + c4);
      float4 d1[4] = {dec4(q1.x), dec4(q1.y), dec4(q1.z), dec4(q1.w)};
      float4 d2[4] = {dec4(q2.x), dec4(q2.y), dec4(q2.z), dec4(q2.w)};
      uint ehall[8] = {eh0.x, eh0.y, eh0.z, eh0.w, eh1.x, eh1.y, eh1.z, eh1.w};
#pragma unroll
      for (int c = 0; c < 4; ++c) {
        float e0 = b2f((ushort)(ehall[2 * c] & 0xFFFFu));
        float e1 = b2f((ushort)(ehall[2 * c] >> 16));
        float e2 = b2f((ushort)(ehall[2 * c + 1] & 0xFFFFu));
        float e3 = b2f((ushort)(ehall[2 * c + 1] >> 16));
        float z0 = (e0 + d1[c].x + d2[c].x) * (1.f / 3.f);
        float z1 = (e1 + d1[c].y + d2[c].y) * (1.f / 3.f);
        float z2 = (e2 + d1[c].z + d2[c].z) * (1.f / 3.f);
        float z3 = (e3 + d1[c].w + d2[c].w) * (1.f / 3.f);
        outp[2 * c] = pack2(z0, z1);
        outp[2 * c + 1] = pack2(z2, z3);
      }
    } else {
#pragma unroll
      for (int c = 0; c < 8; ++c) outp[c] = 0;
    }
    int c0 = c4 * 4;
    *(uint4*)&Pl[row * 72 + c0] = *(uint4*)&outp[0];
    *(uint4*)&Pl[row * 72 + c0 + 8] = *(uint4*)&outp[4];
  }
  __syncthreads();

  // ---- GEMM2: acc2 = H @ W1^T + b1 ----
  const ushort* hap = &Hl[(16 * wid + r15) * 72 + 8 * kg];
  short8v ha0 = *(const short8v*)hap;
  short8v ha1 = *(const short8v*)(hap + 32);
  float4v acc2[4];
#pragma unroll
  for (int b = 0; b < 4; ++b) {
    int col = r15 + 16 * b;
    short8v w0 = *(const short8v*)&Wmh[4096 + col * 64 + 8 * kg];
    short8v w1 = *(const short8v*)&Wmh[4096 + col * 64 + 32 + 8 * kg];
    float bias = bm[64 + col];
    acc2[b] = (float4v){bias, bias, bias, bias};
    acc2[b] = MFMA(ha0, w0, acc2[b]);
    acc2[b] = MFMA(ha1, w1, acc2[b]);
  }
  __syncthreads();
#pragma unroll
  for (int b = 0; b < 4; ++b)
#pragma unroll
    for (int rr = 0; rr < 4; ++rr)
      Hl[(16 * wid + 4 * kg + rr) * 72 + 16 * b + r15] = f2b(fmaxf(acc2[b][rr], 0.f));
  __syncthreads();

  // ---- attention GEMMs ----
  const ushort* pap = &Pl[(16 * wid + r15) * 72 + 8 * kg];
  short8v pa0 = *(const short8v*)pap;
  short8v pa1 = *(const short8v*)(pap + 32);
  const ushort* nap = &Hl[(16 * wid + r15) * 72 + 8 * kg];
  short8v na0 = *(const short8v*)nap;
  short8v na1 = *(const short8v*)(nap + 32);
  float4v ac1[4], ac2[4];
#pragma unroll
  for (int b = 0; b < 4; ++b) {
    int col = r15 + 16 * b;
    short8v w0 = *(const short8v*)&AWh[col * 64 + 8 * kg];
    short8v w1 = *(const short8v*)&AWh[col * 64 + 32 + 8 * kg];
    float bias = ab[col];
    ac1[b] = (float4v){bias, bias, bias, bias};
    ac1[b] = MFMA(pa0, w0, ac1[b]);
    ac1[b] = MFMA(pa1, w1, ac1[b]);
    ac2[b] = (float4v){bias, bias, bias, bias};
    ac2[b] = MFMA(na0, w0, ac2[b]);
    ac2[b] = MFMA(na1, w1, ac2[b]);
  }

  // ---- epilogue: softmax over {w_p, w_n}; Z written into Pl (bf16) ----
  float qv[4];
#pragma unroll
  for (int b = 0; b < 4; ++b) qv[b] = qw[r15 + 16 * b];
#pragma unroll
  for (int rr = 0; rr < 4; ++rr) {
    float wp = 0.f, wn = 0.f;
#pragma unroll
    for (int b = 0; b < 4; ++b) {
      wp += fast_tanh(ac1[b][rr]) * qv[b];
      wn += fast_tanh(ac2[b][rr]) * qv[b];
    }
#pragma unroll
    for (int off = 8; off; off >>= 1) {
      wp += __shfl_xor(wp, off);
      wn += __shfl_xor(wn, off);
    }
    float m = fmaxf(wp, wn);
    float e1 = __expf(wp - m), e2 = __expf(wn - m);
    float inv = 1.f / (e1 + e2);
    float al0 = e1 * inv, al1 = e2 * inv;
    int row_l = 16 * wid + 4 * kg + rr;
#pragma unroll
    for (int b = 0; b < 4; ++b) {
      int li = row_l * 72 + r15 + 16 * b;
      Pl[li] = f2b(al0 * b2f(Pl[li]) + al1 * b2f(Hl[li]));
    }
  }
  __syncthreads();

  // ---- pack Z (bf16 in Pl) -> Z8 (fp8, 64B rows), coalesced ----
  {
    int row = tid >> 2;
    int c0 = (tid & 3) * 16;
    int node = node0 + row;
    if (node < NN) {
      const ushort* zp = &Pl[row * 72 + c0];
      uint4 o;
      o.x = enc4f(b2f(zp[0]), b2f(zp[1]), b2f(zp[2]), b2f(zp[3]));
      o.y = enc4f(b2f(zp[4]), b2f(zp[5]), b2f(zp[6]), b2f(zp[7]));
      o.z = enc4f(b2f(zp[8]), b2f(zp[9]), b2f(zp[10]), b2f(zp[11]));
      o.w = enc4f(b2f(zp[12]), b2f(zp[13]), b2f(zp[14]), b2f(zp[15]));
      *(uint4*)&Z8[(size_t)node * 16 + (tid & 3) * 4] = o;
    }
  }
}

// 16-lane sub-group per batch element (R20 structure); fp8 Z rows (4B/lane).
__global__ __launch_bounds__(256) void k_score(const uint* __restrict__ Z,
                                               const int* __restrict__ u,
                                               const int* __restrict__ v,
                                               const int* __restrict__ n,
                                               const float* __restrict__ w,
                                               float* __restrict__ out, int B, int K) {
  __shared__ float xbuf[16][44];   // K <= 40 (+pad)
  __shared__ float part[16];
  int t = threadIdx.x;
  int wv = t >> 6, lane = t & 63;
  int sg = lane >> 4, sl = lane & 15;
  int bloc = wv * 4 + sg;
  int b = blockIdx.x * 16 + bloc;
  float lossb = 0.f;
  if (b < B) {
    int uid = u[b], vid = v[b];
    float4 u4 = dec4(Z[(size_t)uid * 16 + sl]);
    float4 v4 = dec4(Z[(size_t)vid * 16 + sl]);
    float p = u4.x * v4.x + u4.y * v4.y + u4.z * v4.z + u4.w * v4.w;
#pragma unroll
    for (int off = 8; off; off >>= 1) p += __shfl_xor(p, off);
    float wb = w[b];
    float sgn = (wb > 0.f) ? 1.f : ((wb < 0.f) ? -1.f : 0.f);
    float sp = sgn * p;
    float regl = u4.x * u4.x + u4.y * u4.y + u4.z * u4.z + u4.w * u4.w
               + v4.x * v4.x + v4.y * v4.y + v4.z * v4.z + v4.w * v4.w;
    const int* nb_ = n + (size_t)b * K;
    for (int k = 0; k < K; ++k) {
      int nid = nb_[k];
      float4 n4 = dec4(Z[(size_t)nid * 16 + sl]);
      float d = u4.x * n4.x + u4.y * n4.y + u4.z * n4.z + u4.w * n4.w;
      regl += n4.x * n4.x + n4.y * n4.y + n4.z * n4.z + n4.w * n4.w;
#pragma unroll
      for (int off = 8; off; off >>= 1) d += __shfl_xor(d, off);
      if (sl == 0) xbuf[bloc][k] = sp - d;
    }
#pragma unroll
    for (int off = 8; off; off >>= 1) regl += __shfl_xor(regl, off);
    float sb = 0.f;
    for (int k = sl; k < K; k += 16) {
      float x = xbuf[bloc][k];
      sb += fminf(x, 0.f) - log1pf(__expf(-fabsf(x)));
    }
#pragma unroll
    for (int off = 8; off; off >>= 1) sb += __shfl_xor(sb, off);
    lossb = -sb + 1e-4f * regl;
  }
  if (sl == 0) part[bloc] = (b < B) ? lossb : 0.f;
  __syncthreads();
  if (t == 0) {
    float s = 0.f;
#pragma unroll
    for (int i = 0; i < 16; ++i) s += part[i];
    unsafeAtomicAdd(out, s);
  }
}

extern "C" void kernel_launch(void* const* d_in, const int* in_sizes, int n_in,
                              void* d_out, int out_size, void* d_ws, size_t ws_size,
                              hipStream_t stream) {
  const float* E  = (const float*)d_in[0];
  const float* E2 = (const float*)d_in[1];
  const float* Wm = (const float*)d_in[2];
  const float* bm = (const float*)d_in[3];
  const float* AW = (const float*)d_in[4];
  const float* ab = (const float*)d_in[5];
  const float* qw = (const float*)d_in[6];
  const int*   ei = (const int*)d_in[7];
  const int*   u  = (const int*)d_in[8];
  const int*   v  = (const int*)d_in[9];
  const int*   nn = (const int*)d_in[10];
  const float* w  = (const float*)d_in[11];

  const int NN = in_sizes[0] / 64;        // 150000
  const int NE = in_sizes[7] / 2;         // 3200000
  const int B  = in_sizes[8];             // 16384
  const int K  = in_sizes[10] / B;        // 40
  const int NBKT = (NN + BK_SIZE - 1) / BK_SIZE;   // 293

  const int* src = ei;
  const int* dst = ei + NE;

  // workspace layout
  float*  ws      = (float*)d_ws;
  float*  dinv    = ws;                               // NN floats
  uint*   E8s     = (uint*)(dinv + NN);               // NN*16 uints
  uint*   b1q     = E8s + (size_t)NN * 16;
  uint*   b1s     = b1q + (size_t)NN * 16;
  uint*   b2q     = b1s + (size_t)NN * 16;
  ushort* E2h     = (ushort*)(b2q + (size_t)NN * 16); // NN*64 ushorts
  ushort* Wmh     = E2h + (size_t)NN * 64;            // 8192 ushorts
  ushort* AWh     = Wmh + 8192;                       // 4096 ushorts
  int*    rowptr  = (int*)(AWh + 4096);               // NN+1 ints
  int*    csrc    = rowptr + NN + 1;                  // NE ints
  int*    gcursor = csrc + NE;                        // NBKT ints
  int*    bktbase = gcursor + NBKT;                   // NBKT+1 ints
  uint*   ebuf    = (uint*)(((uintptr_t)(bktbase + NBKT + 1) + 15) & ~(uintptr_t)15);
  // ebuf region (NBKT*CAP*8 B extent) dead after k_fine; reuse:
  uint*   Z8      = ebuf;                             // NN*16 uints (fp8 Z)
  ushort* Ebf     = (ushort*)(Z8 + (size_t)NN * 16);  // NN*64 ushorts
  float*  outf    = (float*)d_out;

  hipMemsetAsync(gcursor, 0, (size_t)NBKT * sizeof(int), stream);
  hipMemsetAsync(outf, 0, sizeof(float), stream);

  const int BUCKET_BLOCKS = 512;
  int chunk = (NE + BUCKET_BLOCKS - 1) / BUCKET_BLOCKS;
  k_bucket<<<BUCKET_BLOCKS, 512, 0, stream>>>(src, dst, gcursor, ebuf, NE, NBKT, chunk);
  k_small<<<1, 1024, 0, stream>>>(gcursor, bktbase, NBKT);
  k_fine<<<NBKT, 256, 0, stream>>>(ebuf, gcursor, bktbase, rowptr, dinv, csrc, NN, NBKT);

  // conversions (after k_fine: dinv ready, Ebf region free)
  k_conv<<<(NN * 4 + 255) / 256, 256, 0, stream>>>(E, E2, dinv, E8s, Ebf, E2h, NN * 4);
  k_convw<<<6, 256, 0, stream>>>(Wm, AW, Wmh, AWh);

  int gatherBlocks = ((size_t)NN * 16 + 255) / 256;   // 16 lanes per node
  k_gather<<<gatherBlocks, 256, 0, stream>>>(E8s, rowptr, csrc, dinv, b1q, b1s, NN);
  k_gather<<<gatherBlocks, 256, 0, stream>>>(b1s, rowptr, csrc, dinv, b2q, (uint*)nullptr, NN);

  int nodeTiles = (NN + 63) / 64;
  k_node<<<nodeTiles, 256, 0, stream>>>(Ebf, E2h, Wmh, bm, AWh, ab, qw, b1q, b2q, Z8, NN);

  k_score<<<(B + 15) / 16, 256, 0, stream>>>(Z8, u, v, nn, w, outf, B, K);
}

// Round 29
// 273.097 us; speedup vs baseline: 1.0184x; 1.0184x over previous
//
#include <hip/hip_runtime.h>
#include <math.h>

// ---------------------------------------------------------------------------
// SiReN loss on MI355X — round 29: revert k_bucket to R27 (simple two-pass,
// measured-best 273us). R28's LDS counting sort fixed k_bucket's scatter but
// cost more than it saved (LDS footprint + scan/copy-out overhead).
// Final configuration: every kernel at its independently-bracketed floor.
// ---------------------------------------------------------------------------

typedef unsigned int uint;
typedef unsigned short ushort;
typedef unsigned long long ull;
typedef __attribute__((ext_vector_type(8))) short short8v;
typedef __attribute__((ext_vector_type(4))) float float4v;
typedef __attribute__((ext_vector_type(2))) float float2v;

#define BK_SHIFT 9
#define BK_SIZE 512
#define CAP 20480
#define SRC_BITS 18
#define SRC_MASK ((1u << SRC_BITS) - 1u)

#if __has_builtin(__builtin_amdgcn_cvt_pk_f32_fp8) && __has_builtin(__builtin_amdgcn_cvt_pk_fp8_f32)
#define HW_FP8 1
#else
#define HW_FP8 0
#endif

__device__ inline float b2f(ushort u) { return __uint_as_float(((uint)u) << 16); }
__device__ inline ushort f2b(float f) {
  uint u = __float_as_uint(f);
  return (ushort)((u + 0x7fffu + ((u >> 16) & 1u)) >> 16);
}
__device__ inline uint pack2(float lo, float hi) {
  return (uint)f2b(lo) | ((uint)f2b(hi) << 16);
}

// ---- fp8 e4m3 helpers ----
__device__ inline float dec1(uint u) {
  uint e = (u >> 3) & 0xFu;
  uint m = u & 7u;
  uint s = (u & 0x80u) << 24;
  float norm = __uint_as_float(s | ((e + 120u) << 23) | (m << 20));
  float den = __uint_as_float(s | 0x3F800000u) * (float)(int)m * 0.001953125f;
  return e ? norm : den;
}
__device__ inline uint enc1(float x) {
  uint s = (__float_as_uint(x) >> 24) & 0x80u;
  float ax = fminf(fabsf(x), 448.f);
  uint r;
  if (ax < 0.015625f) {
    r = (uint)(int)rintf(ax * 512.f);
  } else {
    uint b = __float_as_uint(ax);
    b += 0x7FFFFu + ((b >> 20) & 1u);
    uint e = (b >> 23) - 120u;
    r = (e > 15u) ? 0x7Eu : ((e << 3) | ((b >> 20) & 7u));
  }
  return s | r;
}
__device__ inline float4 dec4(uint v) {
#if HW_FP8
  float2v lo = __builtin_amdgcn_cvt_pk_f32_fp8((int)v, false);
  float2v hi = __builtin_amdgcn_cvt_pk_f32_fp8((int)v, true);
  return make_float4(lo[0], lo[1], hi[0], hi[1]);
#else
  return make_float4(dec1(v & 0xFFu), dec1((v >> 8) & 0xFFu),
                     dec1((v >> 16) & 0xFFu), dec1(v >> 24));
#endif
}
__device__ inline uint enc4f(float a, float b, float c, float d) {
#if HW_FP8
  int v = 0;
  v = __builtin_amdgcn_cvt_pk_fp8_f32(a, b, v, false);
  v = __builtin_amdgcn_cvt_pk_fp8_f32(c, d, v, true);
  return (uint)v;
#else
  return enc1(a) | (enc1(b) << 8) | (enc1(c) << 16) | (enc1(d) << 24);
#endif
}

// fused converter: E -> E8s (fp8, pre-scaled by dinv) + Ebf (bf16), E2 -> E2h.
__global__ void k_conv(const float* __restrict__ E, const float* __restrict__ E2,
                       const float* __restrict__ dinv,
                       uint* __restrict__ E8s, ushort* __restrict__ Ebf,
                       ushort* __restrict__ E2h, int n4) {
  int i = blockIdx.x * blockDim.x + threadIdx.x;
  if (i >= n4) return;
  int node = i >> 2;
  float dn = dinv[node];
  const float4* pe = (const float4*)(E + (size_t)i * 16);
  float4 f0 = pe[0], f1 = pe[1], f2 = pe[2], f3 = pe[3];
  uint4 o8;
  o8.x = enc4f(dn * f0.x, dn * f0.y, dn * f0.z, dn * f0.w);
  o8.y = enc4f(dn * f1.x, dn * f1.y, dn * f1.z, dn * f1.w);
  o8.z = enc4f(dn * f2.x, dn * f2.y, dn * f2.z, dn * f2.w);
  o8.w = enc4f(dn * f3.x, dn * f3.y, dn * f3.z, dn * f3.w);
  ((uint4*)E8s)[i] = o8;
  uint4 h0, h1;
  h0.x = pack2(f0.x, f0.y); h0.y = pack2(f0.z, f0.w);
  h0.z = pack2(f1.x, f1.y); h0.w = pack2(f1.z, f1.w);
  h1.x = pack2(f2.x, f2.y); h1.y = pack2(f2.z, f2.w);
  h1.z = pack2(f3.x, f3.y); h1.w = pack2(f3.z, f3.w);
  ((uint4*)Ebf)[2 * i] = h0;
  ((uint4*)Ebf)[2 * i + 1] = h1;
  const float4* p2 = (const float4*)(E2 + (size_t)i * 16);
  float4 g0 = p2[0], g1 = p2[1], g2 = p2[2], g3 = p2[3];
  uint4 e0, e1;
  e0.x = pack2(g0.x, g0.y); e0.y = pack2(g0.z, g0.w);
  e0.z = pack2(g1.x, g1.y); e0.w = pack2(g1.z, g1.w);
  e1.x = pack2(g2.x, g2.y); e1.y = pack2(g2.z, g2.w);
  e1.z = pack2(g3.x, g3.y); e1.w = pack2(g3.z, g3.w);
  ((uint4*)E2h)[2 * i] = e0;
  ((uint4*)E2h)[2 * i + 1] = e1;
}

// weights: Wm (8192) then AW (4096) -> bf16, thread handles 8 elems
__global__ void k_convw(const float* __restrict__ Wm, const float* __restrict__ AW,
                        ushort* __restrict__ Wmh, ushort* __restrict__ AWh) {
  int i = blockIdx.x * blockDim.x + threadIdx.x;
  const float* srcp;
  ushort* dstp;
  if (i < 1024) { srcp = Wm + (size_t)i * 8; dstp = Wmh + (size_t)i * 8; }
  else if (i < 1536) { srcp = AW + (size_t)(i - 1024) * 8; dstp = AWh + (size_t)(i - 1024) * 8; }
  else return;
  float4 a = ((const float4*)srcp)[0], b = ((const float4*)srcp)[1];
  uint4 o;
  o.x = pack2(a.x, a.y); o.y = pack2(a.z, a.w);
  o.z = pack2(b.x, b.y); o.w = pack2(b.z, b.w);
  *(uint4*)dstp = o;
}

// bucket-partition edges: LDS histogram + one global atomic per (block,bucket).
// 4B packed record: (dl << 18) | src
__global__ __launch_bounds__(512) void k_bucket(const int* __restrict__ src,
                                                const int* __restrict__ dst,
                                                int* __restrict__ gcursor,
                                                uint* __restrict__ ebuf,
                                                int NE, int nbkt, int chunk) {
  __shared__ int hist[1024];
  __shared__ int curb[1024];
  int tid = threadIdx.x;
  int nt = blockDim.x;
  for (int g = tid; g < nbkt; g += nt) hist[g] = 0;
  __syncthreads();
  int lo = blockIdx.x * chunk;
  int hi = min(lo + chunk, NE);
  for (int e = lo + tid; e < hi; e += nt)
    atomicAdd(&hist[dst[e] >> BK_SHIFT], 1);
  __syncthreads();
  for (int g = tid; g < nbkt; g += nt) {
    int c = hist[g];
    curb[g] = (c > 0) ? atomicAdd(&gcursor[g], c) : 0;
  }
  __syncthreads();
  for (int e = lo + tid; e < hi; e += nt) {
    int d = dst[e];
    int g = d >> BK_SHIFT;
    int pos = atomicAdd(&curb[g], 1);
    if (pos < CAP)
      ebuf[(size_t)g * CAP + pos] = ((uint)(d & (BK_SIZE - 1)) << SRC_BITS) | (uint)src[e];
  }
}

// exclusive scan of bucket totals (nbkt <= 1024), single block
__global__ void k_small(const int* __restrict__ gcursor, int* __restrict__ bktbase,
                        int nbkt) {
  __shared__ int sm[1024];
  int t = threadIdx.x;
  int v = (t < nbkt) ? gcursor[t] : 0;
  sm[t] = v;
  __syncthreads();
  for (int off = 1; off < 1024; off <<= 1) {
    int a = (t >= off) ? sm[t - off] : 0;
    __syncthreads();
    sm[t] += a;
    __syncthreads();
  }
  if (t < nbkt) bktbase[t] = sm[t] - v;
  if (t == 0) bktbase[nbkt] = sm[1023];
}

// per-bucket: LDS count -> LDS scan -> rowptr+dinv, then place csrc
__global__ __launch_bounds__(256) void k_fine(const uint* __restrict__ ebuf,
                                              const int* __restrict__ gcursor,
                                              const int* __restrict__ bktbase,
                                              int* __restrict__ rowptr,
                                              float* __restrict__ dinv,
                                              int* __restrict__ csrc,
                                              int NN, int nbkt) {
  __shared__ int degl[BK_SIZE];
  __shared__ int lpl[BK_SIZE];
  __shared__ int ssum[256];
  int g = blockIdx.x;
  int tid = threadIdx.x;
  int cnt = gcursor[g];
  int base = bktbase[g];
  size_t ebase = (size_t)g * CAP;
  for (int j = tid; j < BK_SIZE; j += 256) degl[j] = 0;
  __syncthreads();
  for (int i = tid; i < cnt; i += 256)
    atomicAdd(&degl[(int)(ebuf[ebase + i] >> SRC_BITS)], 1);
  __syncthreads();
  int d0 = degl[2 * tid], d1 = degl[2 * tid + 1];
  int s = d0 + d1;
  ssum[tid] = s;
  __syncthreads();
  for (int off = 1; off < 256; off <<= 1) {
    int a = (tid >= off) ? ssum[tid - off] : 0;
    __syncthreads();
    ssum[tid] += a;
    __syncthreads();
  }
  int excl = ssum[tid] - s;
  lpl[2 * tid] = excl;
  lpl[2 * tid + 1] = excl + d0;
  int node0 = g * BK_SIZE;
  int n0 = node0 + 2 * tid, n1 = n0 + 1;
  if (n0 < NN) {
    rowptr[n0] = base + excl;
    dinv[n0] = (d0 > 0) ? rsqrtf((float)d0) : 0.f;
  }
  if (n1 < NN) {
    rowptr[n1] = base + excl + d0;
    dinv[n1] = (d1 > 0) ? rsqrtf((float)d1) : 0.f;
  }
  if (g == nbkt - 1 && tid == 255) rowptr[NN] = base + excl + d0 + d1;
  __syncthreads();
  for (int i = tid; i < cnt; i += 256) {
    uint e = ebuf[ebase + i];
    int dl = (int)(e >> SRC_BITS);
    int r = atomicAdd(&lpl[dl], 1);
    csrc[base + r] = (int)(e & SRC_MASK);
  }
}

// 16-lane sub-group per node; pre-scaled fp8 rows, no per-edge dinv.
__global__ __launch_bounds__(256) void k_gather(const uint* __restrict__ x,
                                                const int* __restrict__ rowptr,
                                                const int* __restrict__ csrc,
                                                const float* __restrict__ dinv,
                                                uint* __restrict__ out1,
                                                uint* __restrict__ outs, int NN) {
  int gid = blockIdx.x * blockDim.x + threadIdx.x;
  int node = gid >> 4;
  if (node >= NN) return;
  int sl = gid & 15;
  int beg = rowptr[node], end = rowptr[node + 1];
  float dn = dinv[node];
  float a0 = 0.f, a1 = 0.f, a2 = 0.f, a3 = 0.f;
  int i = beg;
  for (; i + 3 < end; i += 4) {
    int s0 = csrc[i], s1 = csrc[i + 1], s2 = csrc[i + 2], s3 = csrc[i + 3];
    uint r0 = x[(size_t)s0 * 16 + sl];
    uint r1 = x[(size_t)s1 * 16 + sl];
    uint r2 = x[(size_t)s2 * 16 + sl];
    uint r3 = x[(size_t)s3 * 16 + sl];
    float4 d0 = dec4(r0), d1 = dec4(r1), d2 = dec4(r2), d3 = dec4(r3);
    a0 += d0.x + d1.x + d2.x + d3.x;
    a1 += d0.y + d1.y + d2.y + d3.y;
    a2 += d0.z + d1.z + d2.z + d3.z;
    a3 += d0.w + d1.w + d2.w + d3.w;
  }
  for (; i < end; ++i) {
    float4 d0 = dec4(x[(size_t)csrc[i] * 16 + sl]);
    a0 += d0.x; a1 += d0.y; a2 += d0.z; a3 += d0.w;
  }
  out1[(size_t)node * 16 + sl] = enc4f(a0 * dn, a1 * dn, a2 * dn, a3 * dn);
  if (outs) {
    float dn2 = dn * dn;
    outs[(size_t)node * 16 + sl] = enc4f(a0 * dn2, a1 * dn2, a2 * dn2, a3 * dn2);
  }
}

// ---------------------------------------------------------------------------
// k_node (MFMA bf16): bf16 E2h A-loads, bf16 Ebf + fp8 b1/b2 ZP; Z packed to
// fp8 (Z8) via an LDS pass (64B rows for k_score).
// ---------------------------------------------------------------------------
__device__ inline float fast_tanh(float x) {
  float t = __expf(fminf(fmaxf(2.f * x, -30.f), 30.f));
  return (t - 1.f) / (t + 1.f);
}

#define MFMA(a, b, c) __builtin_amdgcn_mfma_f32_16x16x32_bf16((a), (b), (c), 0, 0, 0)

__global__ __launch_bounds__(256, 2) void k_node(const ushort* __restrict__ Ebf,
                                                 const ushort* __restrict__ E2h,
                                                 const ushort* __restrict__ Wmh,
                                                 const float* __restrict__ bm,
                                                 const ushort* __restrict__ AWh,
                                                 const float* __restrict__ ab,
                                                 const float* __restrict__ qw,
                                                 const uint* __restrict__ b1q,
                                                 const uint* __restrict__ b2q,
                                                 uint* __restrict__ Z8,
                                                 int NN) {
  __shared__ ushort Hl[64 * 72];
  __shared__ ushort Pl[64 * 72];
  int tid = threadIdx.x;
  int lane = tid & 63, wid = tid >> 6;
  int r15 = lane & 15, kg = lane >> 4;
  int node0 = blockIdx.x * 64;

  // ---- GEMM1: acc = E2 @ W0^T + b0 ----
  int arow = node0 + 16 * wid + r15;
  int arowc = min(arow, NN - 1);
  const ushort* e2p = E2h + (size_t)arowc * 64 + 8 * kg;
  short8v a0 = *(const short8v*)e2p;
  short8v a1 = *(const short8v*)(e2p + 32);
  float4v acc[4];
#pragma unroll
  for (int b = 0; b < 4; ++b) {
    int col = r15 + 16 * b;
    short8v w0 = *(const short8v*)&Wmh[col * 64 + 8 * kg];
    short8v w1 = *(const short8v*)&Wmh[col * 64 + 32 + 8 * kg];
    float bias = bm[col];
    acc[b] = (float4v){bias, bias, bias, bias};
    acc[b] = MFMA(a0, w0, acc[b]);
    acc[b] = MFMA(a1, w1, acc[b]);
  }
#pragma unroll
  for (int b = 0; b < 4; ++b)
#pragma unroll
    for (int rr = 0; rr < 4; ++rr)
      Hl[(16 * wid + 4 * kg + rr) * 72 + 16 * b + r15] = f2b(fmaxf(acc[b][rr], 0.f));

  // stage ZP = (E + b1 + b2)/3 -> Pl (bf16); E bf16, b1/b2 fp8
  {
    int row = tid >> 2;
    int c4 = (tid & 3) * 4;
    int node = node0 + row;
    uint outp[8];
    if (node < NN) {
      const ushort* pe = Ebf + (size_t)node * 64 + c4 * 4;
      uint4 eh0 = *(const uint4*)pe;
      uint4 eh1 = *(const uint4*)(pe + 8);
      uint4 q1 = *(const uint4*)(b1q + (size_t)node * 16 + c4);
      uint4 q2 = *(const uint4*)(b2q + (size_t)node * 16 + c4);
      float4 d1[4] = {dec4(q1.x), dec4(q1.y), dec4(q1.z), dec4(q1.w)};
      float4 d2[4] = {dec4(q2.x), dec4(q2.y), dec4(q2.z), dec4(q2.w)};
      uint ehall[8] = {eh0.x, eh0.y, eh0.z, eh0.w, eh1.x, eh1.y, eh1.z, eh1.w};
#pragma unroll
      for (int c = 0; c < 4; ++c) {
        float e0 = b2f((ushort)(ehall[2 * c] & 0xFFFFu));
        float e1 = b2f((ushort)(ehall[2 * c] >> 16));
        float e2 = b2f((ushort)(ehall[2 * c + 1] & 0xFFFFu));
        float e3 = b2f((ushort)(ehall[2 * c + 1] >> 16));
        float z0 = (e0 + d1[c].x + d2[c].x) * (1.f / 3.f);
        float z1 = (e1 + d1[c].y + d2[c].y) * (1.f / 3.f);
        float z2 = (e2 + d1[c].z + d2[c].z) * (1.f / 3.f);
        float z3 = (e3 + d1[c].w + d2[c].w) * (1.f / 3.f);
        outp[2 * c] = pack2(z0, z1);
        outp[2 * c + 1] = pack2(z2, z3);
      }
    } else {
#pragma unroll
      for (int c = 0; c < 8; ++c) outp[c] = 0;
    }
    int c0 = c4 * 4;
    *(uint4*)&Pl[row * 72 + c0] = *(uint4*)&outp[0];
    *(uint4*)&Pl[row * 72 + c0 + 8] = *(uint4*)&outp[4];
  }
  __syncthreads();

  // ---- GEMM2: acc2 = H @ W1^T + b1 ----
  const ushort* hap = &Hl[(16 * wid + r15) * 72 + 8 * kg];
  short8v ha0 = *(const short8v*)hap;
  short8v ha1 = *(const short8v*)(hap + 32);
  float4v acc2[4];
#pragma unroll
  for (int b = 0; b < 4; ++b) {
    int col = r15 + 16 * b;
    short8v w0 = *(const short8v*)&Wmh[4096 + col * 64 + 8 * kg];
    short8v w1 = *(const short8v*)&Wmh[4096 + col * 64 + 32 + 8 * kg];
    float bias = bm[64 + col];
    acc2[b] = (float4v){bias, bias, bias, bias};
    acc2[b] = MFMA(ha0, w0, acc2[b]);
    acc2[b] = MFMA(ha1, w1, acc2[b]);
  }
  __syncthreads();
#pragma unroll
  for (int b = 0; b < 4; ++b)
#pragma unroll
    for (int rr = 0; rr < 4; ++rr)
      Hl[(16 * wid + 4 * kg + rr) * 72 + 16 * b + r15] = f2b(fmaxf(acc2[b][rr], 0.f));
  __syncthreads();

  // ---- attention GEMMs ----
  const ushort* pap = &Pl[(16 * wid + r15) * 72 + 8 * kg];
  short8v pa0 = *(const short8v*)pap;
  short8v pa1 = *(const short8v*)(pap + 32);
  const ushort* nap = &Hl[(16 * wid + r15) * 72 + 8 * kg];
  short8v na0 = *(const short8v*)nap;
  short8v na1 = *(const short8v*)(nap + 32);
  float4v ac1[4], ac2[4];
#pragma unroll
  for (int b = 0; b < 4; ++b) {
    int col = r15 + 16 * b;
    short8v w0 = *(const short8v*)&AWh[col * 64 + 8 * kg];
    short8v w1 = *(const short8v*)&AWh[col * 64 + 32 + 8 * kg];
    float bias = ab[col];
    ac1[b] = (float4v){bias, bias, bias, bias};
    ac1[b] = MFMA(pa0, w0, ac1[b]);
    ac1[b] = MFMA(pa1, w1, ac1[b]);
    ac2[b] = (float4v){bias, bias, bias, bias};
    ac2[b] = MFMA(na0, w0, ac2[b]);
    ac2[b] = MFMA(na1, w1, ac2[b]);
  }

  // ---- epilogue: softmax over {w_p, w_n}; Z written into Pl (bf16) ----
  float qv[4];
#pragma unroll
  for (int b = 0; b < 4; ++b) qv[b] = qw[r15 + 16 * b];
#pragma unroll
  for (int rr = 0; rr < 4; ++rr) {
    float wp = 0.f, wn = 0.f;
#pragma unroll
    for (int b = 0; b < 4; ++b) {
      wp += fast_tanh(ac1[b][rr]) * qv[b];
      wn += fast_tanh(ac2[b][rr]) * qv[b];
    }
#pragma unroll
    for (int off = 8; off; off >>= 1) {
      wp += __shfl_xor(wp, off);
      wn += __shfl_xor(wn, off);
    }
    float m = fmaxf(wp, wn);
    float e1 = __expf(wp - m), e2 = __expf(wn - m);
    float inv = 1.f / (e1 + e2);
    float al0 = e1 * inv, al1 = e2 * inv;
    int row_l = 16 * wid + 4 * kg + rr;
#pragma unroll
    for (int b = 0; b < 4; ++b) {
      int li = row_l * 72 + r15 + 16 * b;
      Pl[li] = f2b(al0 * b2f(Pl[li]) + al1 * b2f(Hl[li]));
    }
  }
  __syncthreads();

  // ---- pack Z (bf16 in Pl) -> Z8 (fp8, 64B rows), coalesced ----
  {
    int row = tid >> 2;
    int c0 = (tid & 3) * 16;
    int node = node0 + row;
    if (node < NN) {
      const ushort* zp = &Pl[row * 72 + c0];
      uint4 o;
      o.x = enc4f(b2f(zp[0]), b2f(zp[1]), b2f(zp[2]), b2f(zp[3]));
      o.y = enc4f(b2f(zp[4]), b2f(zp[5]), b2f(zp[6]), b2f(zp[7]));
      o.z = enc4f(b2f(zp[8]), b2f(zp[9]), b2f(zp[10]), b2f(zp[11]));
      o.w = enc4f(b2f(zp[12]), b2f(zp[13]), b2f(zp[14]), b2f(zp[15]));
      *(uint4*)&Z8[(size_t)node * 16 + (tid & 3) * 4] = o;
    }
  }
}

// 16-lane sub-group per batch element (R20 structure); fp8 Z rows (4B/lane).
__global__ __launch_bounds__(256) void k_score(const uint* __restrict__ Z,
                                               const int* __restrict__ u,
                                               const int* __restrict__ v,
                                               const int* __restrict__ n,
                                               const float* __restrict__ w,
                                               float* __restrict__ out, int B, int K) {
  __shared__ float xbuf[16][44];   // K <= 40 (+pad)
  __shared__ float part[16];
  int t = threadIdx.x;
  int wv = t >> 6, lane = t & 63;
  int sg = lane >> 4, sl = lane & 15;
  int bloc = wv * 4 + sg;
  int b = blockIdx.x * 16 + bloc;
  float lossb = 0.f;
  if (b < B) {
    int uid = u[b], vid = v[b];
    float4 u4 = dec4(Z[(size_t)uid * 16 + sl]);
    float4 v4 = dec4(Z[(size_t)vid * 16 + sl]);
    float p = u4.x * v4.x + u4.y * v4.y + u4.z * v4.z + u4.w * v4.w;
#pragma unroll
    for (int off = 8; off; off >>= 1) p += __shfl_xor(p, off);
    float wb = w[b];
    float sgn = (wb > 0.f) ? 1.f : ((wb < 0.f) ? -1.f : 0.f);
    float sp = sgn * p;
    float regl = u4.x * u4.x + u4.y * u4.y + u4.z * u4.z + u4.w * u4.w
               + v4.x * v4.x + v4.y * v4.y + v4.z * v4.z + v4.w * v4.w;
    const int* nb_ = n + (size_t)b * K;
    for (int k = 0; k < K; ++k) {
      int nid = nb_[k];
      float4 n4 = dec4(Z[(size_t)nid * 16 + sl]);
      float d = u4.x * n4.x + u4.y * n4.y + u4.z * n4.z + u4.w * n4.w;
      regl += n4.x * n4.x + n4.y * n4.y + n4.z * n4.z + n4.w * n4.w;
#pragma unroll
      for (int off = 8; off; off >>= 1) d += __shfl_xor(d, off);
      if (sl == 0) xbuf[bloc][k] = sp - d;
    }
#pragma unroll
    for (int off = 8; off; off >>= 1) regl += __shfl_xor(regl, off);
    float sb = 0.f;
    for (int k = sl; k < K; k += 16) {
      float x = xbuf[bloc][k];
      sb += fminf(x, 0.f) - log1pf(__expf(-fabsf(x)));
    }
#pragma unroll
    for (int off = 8; off; off >>= 1) sb += __shfl_xor(sb, off);
    lossb = -sb + 1e-4f * regl;
  }
  if (sl == 0) part[bloc] = (b < B) ? lossb : 0.f;
  __syncthreads();
  if (t == 0) {
    float s = 0.f;
#pragma unroll
    for (int i = 0; i < 16; ++i) s += part[i];
    unsafeAtomicAdd(out, s);
  }
}

extern "C" void kernel_launch(void* const* d_in, const int* in_sizes, int n_in,
                              void* d_out, int out_size, void* d_ws, size_t ws_size,
                              hipStream_t stream) {
  const float* E  = (const float*)d_in[0];
  const float* E2 = (const float*)d_in[1];
  const float* Wm = (const float*)d_in[2];
  const float* bm = (const float*)d_in[3];
  const float* AW = (const float*)d_in[4];
  const float* ab = (const float*)d_in[5];
  const float* qw = (const float*)d_in[6];
  const int*   ei = (const int*)d_in[7];
  const int*   u  = (const int*)d_in[8];
  const int*   v  = (const int*)d_in[9];
  const int*   nn = (const int*)d_in[10];
  const float* w  = (const float*)d_in[11];

  const int NN = in_sizes[0] / 64;        // 150000
  const int NE = in_sizes[7] / 2;         // 3200000
  const int B  = in_sizes[8];             // 16384
  const int K  = in_sizes[10] / B;        // 40
  const int NBKT = (NN + BK_SIZE - 1) / BK_SIZE;   // 293

  const int* src = ei;
  const int* dst = ei + NE;

  // workspace layout
  float*  ws      = (float*)d_ws;
  float*  dinv    = ws;                               // NN floats
  uint*   E8s     = (uint*)(dinv + NN);               // NN*16 uints
  uint*   b1q     = E8s + (size_t)NN * 16;
  uint*   b1s     = b1q + (size_t)NN * 16;
  uint*   b2q     = b1s + (size_t)NN * 16;
  ushort* E2h     = (ushort*)(b2q + (size_t)NN * 16); // NN*64 ushorts
  ushort* Wmh     = E2h + (size_t)NN * 64;            // 8192 ushorts
  ushort* AWh     = Wmh + 8192;                       // 4096 ushorts
  int*    rowptr  = (int*)(AWh + 4096);               // NN+1 ints
  int*    csrc    = rowptr + NN + 1;                  // NE ints
  int*    gcursor = csrc + NE;                        // NBKT ints
  int*    bktbase = gcursor + NBKT;                   // NBKT+1 ints
  uint*   ebuf    = (uint*)(((uintptr_t)(bktbase + NBKT + 1) + 15) & ~(uintptr_t)15);
  // ebuf region (NBKT*CAP*8 B extent) dead after k_fine; reuse:
  uint*   Z8      = ebuf;                             // NN*16 uints (fp8 Z)
  ushort* Ebf     = (ushort*)(Z8 + (size_t)NN * 16);  // NN*64 ushorts
  float*  outf    = (float*)d_out;

  hipMemsetAsync(gcursor, 0, (size_t)NBKT * sizeof(int), stream);
  hipMemsetAsync(outf, 0, sizeof(float), stream);

  const int BUCKET_BLOCKS = 512;
  int chunk = (NE + BUCKET_BLOCKS - 1) / BUCKET_BLOCKS;
  k_bucket<<<BUCKET_BLOCKS, 512, 0, stream>>>(src, dst, gcursor, ebuf, NE, NBKT, chunk);
  k_small<<<1, 1024, 0, stream>>>(gcursor, bktbase, NBKT);
  k_fine<<<NBKT, 256, 0, stream>>>(ebuf, gcursor, bktbase, rowptr, dinv, csrc, NN, NBKT);

  // conversions (after k_fine: dinv ready, Ebf region free)
  k_conv<<<(NN * 4 + 255) / 256, 256, 0, stream>>>(E, E2, dinv, E8s, Ebf, E2h, NN * 4);
  k_convw<<<6, 256, 0, stream>>>(Wm, AW, Wmh, AWh);

  int gatherBlocks = ((size_t)NN * 16 + 255) / 256;   // 16 lanes per node
  k_gather<<<gatherBlocks, 256, 0, stream>>>(E8s, rowptr, csrc, dinv, b1q, b1s, NN);
  k_gather<<<gatherBlocks, 256, 0, stream>>>(b1s, rowptr, csrc, dinv, b2q, (uint*)nullptr, NN);

  int nodeTiles = (NN + 63) / 64;
  k_node<<<nodeTiles, 256, 0, stream>>>(Ebf, E2h, Wmh, bm, AWh, ab, qw, b1q, b2q, Z8, NN);

  k_score<<<(B + 15) / 16, 256, 0, stream>>>(Z8, u, v, nn, w, outf, B, K);
}